// Round 3
// baseline (1495.676 us; speedup 1.0000x reference)
//
#include <hip/hip_runtime.h>

// COO SpMM: out[b,d] = sum_{e: row[e]==d} vals[e] * x[b, col[e]] + bias[d]
// B=64 (one wave), NUM_SRC=NUM_DST=100000, NNZ=3.2M, all fp32.
//
// R3: learned from counters that global float atomics WRITE THROUGH to HBM
// (R2: WRITE_SIZE == nnz*256B exactly) and random 8B scatter amplifies to
// 64B/edge (R1: 200MB). So: bin destinations at 128 granularity, tile
// counting-sort scatter (coalesced runs, few int atomics), then per-bin
// LDS accumulation with ds float atomics and a fused transposed epilogue.

#define BINSHIFT 7
#define BINSIZE 128
#define MAXBINS 1024
#define TILE 8192
#define EPT 32  // edges per thread in scatter (TILE = EPT*256)

// ---------- transpose x (B=64, nsrc) -> xT (nsrc, 64) ----------
__global__ __launch_bounds__(1024) void transpose_x_kernel(
    const float* __restrict__ x, float* __restrict__ xT, int nsrc) {
  __shared__ float tile[64][65];
  int s0 = blockIdx.x * 64;
  int tx = threadIdx.x;  // 0..63
  int ty = threadIdx.y;  // 0..15
#pragma unroll
  for (int i = 0; i < 4; ++i) {
    int b = ty + i * 16;
    int s = s0 + tx;
    tile[tx][b] = (s < nsrc) ? x[(size_t)b * nsrc + s] : 0.f;
  }
  __syncthreads();
#pragma unroll
  for (int i = 0; i < 4; ++i) {
    int sl = ty + i * 16;
    int s = s0 + sl;
    if (s < nsrc) xT[(size_t)s * 64 + tx] = tile[sl][tx];
  }
}

// ---------- per-bin histogram (LDS-local, then one global merge) ----------
__global__ __launch_bounds__(256) void bin_hist_kernel(
    const int* __restrict__ row, int* __restrict__ binCnt, int nnz, int nbins) {
  __shared__ int h[MAXBINS];
  for (int j = threadIdx.x; j < nbins; j += 256) h[j] = 0;
  __syncthreads();
  int stride = gridDim.x * 256;
  for (int i = blockIdx.x * 256 + threadIdx.x; i < nnz; i += stride)
    atomicAdd(&h[row[i] >> BINSHIFT], 1);
  __syncthreads();
  for (int j = threadIdx.x; j < nbins; j += 256) {
    int v = h[j];
    if (v) atomicAdd(&binCnt[j], v);
  }
}

// ---------- exclusive scan of bin counts -> base, cursor ----------
__global__ __launch_bounds__(1024) void bin_scan_kernel(
    const int* __restrict__ binCnt, int* __restrict__ base,
    int* __restrict__ cursor, int nbins, int nnz) {
  __shared__ int tmp[1024];
  int t = threadIdx.x;
  int v = (t < nbins) ? binCnt[t] : 0;
  tmp[t] = v;
  __syncthreads();
#pragma unroll
  for (int o = 1; o < 1024; o <<= 1) {
    int a = (t >= o) ? tmp[t - o] : 0;
    __syncthreads();
    tmp[t] += a;
    __syncthreads();
  }
  if (t < nbins) {
    int ex = tmp[t] - v;
    base[t] = ex;
    cursor[t] = ex;
  }
  if (t == 0) base[nbins] = nnz;
}

// ---------- tile counting-sort scatter into binned (rc, v) arrays ----------
__global__ __launch_bounds__(256) void bin_scatter_kernel(
    const int* __restrict__ row, const int* __restrict__ col,
    const float* __restrict__ vals, int* __restrict__ cursor,
    int2* __restrict__ rc, float* __restrict__ vv, int nnz, int nbins) {
  __shared__ int cnt[MAXBINS];
  __shared__ int tb[MAXBINS];
  const int t0 = blockIdx.x * TILE;
  for (int j = threadIdx.x; j < nbins; j += 256) cnt[j] = 0;
  __syncthreads();
  int rank[EPT];
#pragma unroll
  for (int k = 0; k < EPT; ++k) {
    int e = t0 + k * 256 + threadIdx.x;
    if (e < nnz) rank[k] = atomicAdd(&cnt[row[e] >> BINSHIFT], 1);
  }
  __syncthreads();
  // one global int cursor atomic per (tile, nonempty bin)
  for (int j = threadIdx.x; j < nbins; j += 256) {
    int n = cnt[j];
    tb[j] = n ? atomicAdd(&cursor[j], n) : 0;
  }
  __syncthreads();
#pragma unroll
  for (int k = 0; k < EPT; ++k) {
    int e = t0 + k * 256 + threadIdx.x;
    if (e < nnz) {
      int r = row[e], c = col[e];
      float v = vals[e];
      int b = r >> BINSHIFT;
      int pos = tb[b] + rank[k];
      rc[pos] = make_int2(r, c);
      vv[pos] = v;
    }
  }
}

// ---------- per-bin accumulate in LDS + fused transposed epilogue ----------
__global__ __launch_bounds__(256) void bin_acc_kernel(
    const int2* __restrict__ rc, const float* __restrict__ vv,
    const int* __restrict__ base, const float* __restrict__ xT,
    const float* __restrict__ bias, float* __restrict__ out, int ndst) {
  __shared__ float acc[BINSIZE * 65];
  for (int j = threadIdx.x; j < BINSIZE * 65; j += 256) acc[j] = 0.f;
  __syncthreads();
  const int b = blockIdx.x;
  const int start = base[b], end = base[b + 1];
  const int lane = threadIdx.x & 63;
  const int w = threadIdx.x >> 6;  // 0..3
  for (int e0 = start + w * 4; e0 < end; e0 += 16) {
#pragma unroll
    for (int k = 0; k < 4; ++k) {
      int e = e0 + k;
      if (e < end) {  // wave-uniform predicate
        int2 p = rc[e];
        float v = vv[e];
        float xv = xT[((size_t)p.y << 6) + lane];
        atomicAdd(&acc[(p.x & (BINSIZE - 1)) * 65 + lane], v * xv);
      }
    }
  }
  __syncthreads();
  // epilogue: out[br, d0+dloc] = acc[dloc][br] + bias[d]
  const int d0 = b << BINSHIFT;
  for (int i = threadIdx.x; i < BINSIZE * 64; i += 256) {
    int dloc = i & (BINSIZE - 1);  // consecutive lanes -> consecutive d
    int br = i >> BINSHIFT;
    int d = d0 + dloc;
    if (d < ndst) out[(size_t)br * ndst + d] = acc[dloc * 65 + br] + bias[d];
  }
}

extern "C" void kernel_launch(void* const* d_in, const int* in_sizes, int n_in,
                              void* d_out, int out_size, void* d_ws, size_t ws_size,
                              hipStream_t stream) {
  const float* x = (const float*)d_in[0];
  const float* vals = (const float*)d_in[1];
  const float* bias = (const float*)d_in[2];
  const int* row = (const int*)d_in[3];
  const int* col = (const int*)d_in[4];
  float* out = (float*)d_out;

  const int nnz = in_sizes[1];
  const int ndst = in_sizes[2];
  const int B = out_size / ndst;  // == 64 for this problem
  const int nsrc = in_sizes[0] / B;
  const int nbins = (ndst + BINSIZE - 1) >> BINSHIFT;  // 782 <= MAXBINS

  // workspace layout (256B-aligned chunks)
  size_t off = 0;
  auto take = [&](size_t bytes) {
    void* p = (char*)d_ws + off;
    off += (bytes + 255) & ~(size_t)255;
    return p;
  };
  float* xT = (float*)take((size_t)nsrc * 64 * 4);
  int2* rc = (int2*)take((size_t)nnz * 8);
  float* vv = (float*)take((size_t)nnz * 4);
  int* base = (int*)take((size_t)(nbins + 1) * 4);
  int* cursor = (int*)take((size_t)nbins * 4);
  int* binCnt = (int*)take((size_t)nbins * 4);
  (void)ws_size;

  hipMemsetAsync(binCnt, 0, (size_t)nbins * 4, stream);

  // 1. transpose x -> xT
  {
    dim3 blk(64, 16);
    int grid = (nsrc + 63) / 64;
    transpose_x_kernel<<<grid, blk, 0, stream>>>(x, xT, nsrc);
  }
  // 2. per-bin histogram
  bin_hist_kernel<<<512, 256, 0, stream>>>(row, binCnt, nnz, nbins);
  // 3. scan -> base, cursor
  bin_scan_kernel<<<1, 1024, 0, stream>>>(binCnt, base, cursor, nbins, nnz);
  // 4. tile counting-sort scatter
  {
    int grid = (nnz + TILE - 1) / TILE;
    bin_scatter_kernel<<<grid, 256, 0, stream>>>(row, col, vals, cursor, rc, vv,
                                                 nnz, nbins);
  }
  // 5. per-bin LDS accumulate + fused epilogue
  bin_acc_kernel<<<nbins, 256, 0, stream>>>(rc, vv, base, xT, bias, out, ndst);
}

// Round 4
// 1471.319 us; speedup vs baseline: 1.0166x; 1.0166x over previous
//
#include <hip/hip_runtime.h>

// COO SpMM: out[b,d] = sum_{e: row[e]==d} vals[e] * x[b, col[e]] + bias[d]
// B=64 (one wave), NUM_SRC=NUM_DST=100000, NNZ=3.2M, all fp32.
//
// R4: R3's bin_acc was latency-bound (occ 22.9%, 283 GB/s, serial per-edge
// chains). Fix: 8 waves/block, contiguous per-wave ranges with unroll-8
// batched loads (8 gathers in flight), relaxed workgroup-scope ds_add_f32,
// and (col,dloc) packed into one int to shave pair traffic.

#define BINSHIFT 7
#define BINSIZE 128
#define ACCPAD 65
#define MAXBINS 1024
#define TILE 8192
#define EPT 32  // edges per thread in scatter (TILE = EPT*256)

// ---------- transpose x (B=64, nsrc) -> xT (nsrc, 64) ----------
__global__ __launch_bounds__(1024) void transpose_x_kernel(
    const float* __restrict__ x, float* __restrict__ xT, int nsrc) {
  __shared__ float tile[64][65];
  int s0 = blockIdx.x * 64;
  int tx = threadIdx.x;  // 0..63
  int ty = threadIdx.y;  // 0..15
#pragma unroll
  for (int i = 0; i < 4; ++i) {
    int b = ty + i * 16;
    int s = s0 + tx;
    tile[tx][b] = (s < nsrc) ? x[(size_t)b * nsrc + s] : 0.f;
  }
  __syncthreads();
#pragma unroll
  for (int i = 0; i < 4; ++i) {
    int sl = ty + i * 16;
    int s = s0 + sl;
    if (s < nsrc) xT[(size_t)s * 64 + tx] = tile[sl][tx];
  }
}

// ---------- per-bin histogram (LDS-local, then one global merge) ----------
__global__ __launch_bounds__(256) void bin_hist_kernel(
    const int* __restrict__ row, int* __restrict__ binCnt, int nnz, int nbins) {
  __shared__ int h[MAXBINS];
  for (int j = threadIdx.x; j < nbins; j += 256) h[j] = 0;
  __syncthreads();
  int stride = gridDim.x * 256;
  for (int i = blockIdx.x * 256 + threadIdx.x; i < nnz; i += stride)
    atomicAdd(&h[row[i] >> BINSHIFT], 1);
  __syncthreads();
  for (int j = threadIdx.x; j < nbins; j += 256) {
    int v = h[j];
    if (v) atomicAdd(&binCnt[j], v);
  }
}

// ---------- exclusive scan of bin counts -> base, cursor ----------
__global__ __launch_bounds__(1024) void bin_scan_kernel(
    const int* __restrict__ binCnt, int* __restrict__ base,
    int* __restrict__ cursor, int nbins, int nnz) {
  __shared__ int tmp[1024];
  int t = threadIdx.x;
  int v = (t < nbins) ? binCnt[t] : 0;
  tmp[t] = v;
  __syncthreads();
#pragma unroll
  for (int o = 1; o < 1024; o <<= 1) {
    int a = (t >= o) ? tmp[t - o] : 0;
    __syncthreads();
    tmp[t] += a;
    __syncthreads();
  }
  if (t < nbins) {
    int ex = tmp[t] - v;
    base[t] = ex;
    cursor[t] = ex;
  }
  if (t == 0) base[nbins] = nnz;
}

// ---------- tile counting-sort scatter into binned (pk, v) arrays ----------
// pk = (col << 7) | (row & 127)   [needs nsrc < 2^25 — holds here]
__global__ __launch_bounds__(256) void bin_scatter_kernel(
    const int* __restrict__ row, const int* __restrict__ col,
    const float* __restrict__ vals, int* __restrict__ cursor,
    int* __restrict__ pk, float* __restrict__ vv, int nnz, int nbins) {
  __shared__ int cnt[MAXBINS];
  __shared__ int tb[MAXBINS];
  const int t0 = blockIdx.x * TILE;
  for (int j = threadIdx.x; j < nbins; j += 256) cnt[j] = 0;
  __syncthreads();
  int rank[EPT];
#pragma unroll
  for (int k = 0; k < EPT; ++k) {
    int e = t0 + k * 256 + threadIdx.x;
    if (e < nnz) rank[k] = atomicAdd(&cnt[row[e] >> BINSHIFT], 1);
  }
  __syncthreads();
  // one global int cursor atomic per (tile, nonempty bin)
  for (int j = threadIdx.x; j < nbins; j += 256) {
    int n = cnt[j];
    tb[j] = n ? atomicAdd(&cursor[j], n) : 0;
  }
  __syncthreads();
#pragma unroll
  for (int k = 0; k < EPT; ++k) {
    int e = t0 + k * 256 + threadIdx.x;
    if (e < nnz) {
      int r = row[e], c = col[e];
      float v = vals[e];
      int b = r >> BINSHIFT;
      int pos = tb[b] + rank[k];
      pk[pos] = (c << BINSHIFT) | (r & (BINSIZE - 1));
      vv[pos] = v;
    }
  }
}

// ---------- per-bin accumulate in LDS + fused transposed epilogue ----------
__global__ __launch_bounds__(512) void bin_acc_kernel(
    const int* __restrict__ pk, const float* __restrict__ vv,
    const int* __restrict__ base, const float* __restrict__ xT,
    const float* __restrict__ bias, float* __restrict__ out, int ndst) {
  __shared__ float acc[BINSIZE * ACCPAD];
  for (int j = threadIdx.x; j < BINSIZE * ACCPAD; j += 512) acc[j] = 0.f;
  __syncthreads();
  const int b = blockIdx.x;
  const int start = base[b], end = base[b + 1];
  const int lane = threadIdx.x & 63;
  const int w = threadIdx.x >> 6;  // 0..7
  // contiguous per-wave range
  const int nE = end - start;
  const int per = (nE + 7) >> 3;
  const int ws = start + w * per;
  const int weRaw = ws + per;
  const int we = (weRaw < end) ? weRaw : end;
  int e = ws;
  for (; e + 8 <= we; e += 8) {
    int p[8];
    float v[8];
#pragma unroll
    for (int k = 0; k < 8; ++k) {
      p[k] = pk[e + k];
      v[k] = vv[e + k];
    }
    float xv[8];
#pragma unroll
    for (int k = 0; k < 8; ++k)
      xv[k] = xT[((size_t)(p[k] >> BINSHIFT) << 6) + lane];
#pragma unroll
    for (int k = 0; k < 8; ++k)
      (void)__hip_atomic_fetch_add(
          &acc[(p[k] & (BINSIZE - 1)) * ACCPAD + lane], v[k] * xv[k],
          __ATOMIC_RELAXED, __HIP_MEMORY_SCOPE_WORKGROUP);
  }
  for (; e < we; ++e) {
    int p = pk[e];
    float v = vv[e];
    float xv = xT[((size_t)(p >> BINSHIFT) << 6) + lane];
    (void)__hip_atomic_fetch_add(&acc[(p & (BINSIZE - 1)) * ACCPAD + lane],
                                 v * xv, __ATOMIC_RELAXED,
                                 __HIP_MEMORY_SCOPE_WORKGROUP);
  }
  __syncthreads();
  // epilogue: out[br, d0+dloc] = acc[dloc][br] + bias[d]
  const int d0 = b << BINSHIFT;
  for (int i = threadIdx.x; i < BINSIZE * 64; i += 512) {
    int dloc = i & (BINSIZE - 1);  // consecutive lanes -> consecutive d
    int br = i >> BINSHIFT;
    int d = d0 + dloc;
    if (d < ndst) out[(size_t)br * ndst + d] = acc[dloc * ACCPAD + br] + bias[d];
  }
}

extern "C" void kernel_launch(void* const* d_in, const int* in_sizes, int n_in,
                              void* d_out, int out_size, void* d_ws, size_t ws_size,
                              hipStream_t stream) {
  const float* x = (const float*)d_in[0];
  const float* vals = (const float*)d_in[1];
  const float* bias = (const float*)d_in[2];
  const int* row = (const int*)d_in[3];
  const int* col = (const int*)d_in[4];
  float* out = (float*)d_out;

  const int nnz = in_sizes[1];
  const int ndst = in_sizes[2];
  const int B = out_size / ndst;  // == 64 for this problem
  const int nsrc = in_sizes[0] / B;
  const int nbins = (ndst + BINSIZE - 1) >> BINSHIFT;  // 782 <= MAXBINS

  // workspace layout (256B-aligned chunks)
  size_t off = 0;
  auto take = [&](size_t bytes) {
    void* p = (char*)d_ws + off;
    off += (bytes + 255) & ~(size_t)255;
    return p;
  };
  float* xT = (float*)take((size_t)nsrc * 64 * 4);
  int* pk = (int*)take((size_t)nnz * 4);
  float* vv = (float*)take((size_t)nnz * 4);
  int* base = (int*)take((size_t)(nbins + 1) * 4);
  int* cursor = (int*)take((size_t)nbins * 4);
  int* binCnt = (int*)take((size_t)nbins * 4);
  (void)ws_size;

  hipMemsetAsync(binCnt, 0, (size_t)nbins * 4, stream);

  // 1. transpose x -> xT
  {
    dim3 blk(64, 16);
    int grid = (nsrc + 63) / 64;
    transpose_x_kernel<<<grid, blk, 0, stream>>>(x, xT, nsrc);
  }
  // 2. per-bin histogram
  bin_hist_kernel<<<512, 256, 0, stream>>>(row, binCnt, nnz, nbins);
  // 3. scan -> base, cursor
  bin_scan_kernel<<<1, 1024, 0, stream>>>(binCnt, base, cursor, nbins, nnz);
  // 4. tile counting-sort scatter
  {
    int grid = (nnz + TILE - 1) / TILE;
    bin_scatter_kernel<<<grid, 256, 0, stream>>>(row, col, vals, cursor, pk, vv,
                                                 nnz, nbins);
  }
  // 5. per-bin LDS accumulate + fused epilogue
  bin_acc_kernel<<<nbins, 512, 0, stream>>>(pk, vv, base, xT, bias, out, ndst);
}

// Round 5
// 296.667 us; speedup vs baseline: 5.0416x; 4.9595x over previous
//
#include <hip/hip_runtime.h>

// COO SpMM: out[b,d] = sum_{e: row[e]==d} vals[e] * x[b, col[e]] + bias[d]
// B=64 (one wave), NUM_SRC=NUM_DST=100000, NNZ=3.2M, all fp32.
//
// R5: R3/R4 showed wave-wide LDS float atomics per edge are a serialized
// resource (1354us at 3% VALU, flat vs occupancy). Go back to register
// accumulation: build exact CSR in two cheap stages (binned coalesced
// scatter -> per-bin LDS counting sort), then one-wave-per-dst-row spmm
// with scalar (SGPR) edge streams and 8-deep gather batches. No atomics
// on the hot path.

#define BINSHIFT 7
#define BINSIZE 128
#define MAXBINS 1024
#define TILE 8192
#define EPT 32  // edges per thread in scatter (TILE = EPT*256)

// ---------- transpose x (B=64, nsrc) -> xT (nsrc, 64) ----------
__global__ __launch_bounds__(1024) void transpose_x_kernel(
    const float* __restrict__ x, float* __restrict__ xT, int nsrc) {
  __shared__ float tile[64][65];
  int s0 = blockIdx.x * 64;
  int tx = threadIdx.x;  // 0..63
  int ty = threadIdx.y;  // 0..15
#pragma unroll
  for (int i = 0; i < 4; ++i) {
    int b = ty + i * 16;
    int s = s0 + tx;
    tile[tx][b] = (s < nsrc) ? x[(size_t)b * nsrc + s] : 0.f;
  }
  __syncthreads();
#pragma unroll
  for (int i = 0; i < 4; ++i) {
    int sl = ty + i * 16;
    int s = s0 + sl;
    if (s < nsrc) xT[(size_t)s * 64 + tx] = tile[sl][tx];
  }
}

// ---------- per-bin histogram (LDS-local, then one global merge) ----------
__global__ __launch_bounds__(256) void bin_hist_kernel(
    const int* __restrict__ row, int* __restrict__ binCnt, int nnz, int nbins) {
  __shared__ int h[MAXBINS];
  for (int j = threadIdx.x; j < nbins; j += 256) h[j] = 0;
  __syncthreads();
  int stride = gridDim.x * 256;
  for (int i = blockIdx.x * 256 + threadIdx.x; i < nnz; i += stride)
    atomicAdd(&h[row[i] >> BINSHIFT], 1);
  __syncthreads();
  for (int j = threadIdx.x; j < nbins; j += 256) {
    int v = h[j];
    if (v) atomicAdd(&binCnt[j], v);
  }
}

// ---------- exclusive scan of bin counts -> binbase, cursor ----------
__global__ __launch_bounds__(1024) void bin_scan_kernel(
    const int* __restrict__ binCnt, int* __restrict__ binbase,
    int* __restrict__ cursor, int nbins, int nnz) {
  __shared__ int tmp[1024];
  int t = threadIdx.x;
  int v = (t < nbins) ? binCnt[t] : 0;
  tmp[t] = v;
  __syncthreads();
#pragma unroll
  for (int o = 1; o < 1024; o <<= 1) {
    int a = (t >= o) ? tmp[t - o] : 0;
    __syncthreads();
    tmp[t] += a;
    __syncthreads();
  }
  if (t < nbins) {
    int ex = tmp[t] - v;
    binbase[t] = ex;
    cursor[t] = ex;
  }
  if (t == 0) binbase[nbins] = nnz;
}

// ---------- tile counting-sort scatter into binned (pk, v) arrays ----------
// pk = (col << 7) | (row & 127)
__global__ __launch_bounds__(256) void bin_scatter_kernel(
    const int* __restrict__ row, const int* __restrict__ col,
    const float* __restrict__ vals, int* __restrict__ cursor,
    int* __restrict__ pk, float* __restrict__ vv, int nnz, int nbins) {
  __shared__ int cnt[MAXBINS];
  __shared__ int tb[MAXBINS];
  const int t0 = blockIdx.x * TILE;
  for (int j = threadIdx.x; j < nbins; j += 256) cnt[j] = 0;
  __syncthreads();
  int rank[EPT];
#pragma unroll
  for (int k = 0; k < EPT; ++k) {
    int e = t0 + k * 256 + threadIdx.x;
    if (e < nnz) rank[k] = atomicAdd(&cnt[row[e] >> BINSHIFT], 1);
  }
  __syncthreads();
  for (int j = threadIdx.x; j < nbins; j += 256) {
    int n = cnt[j];
    tb[j] = n ? atomicAdd(&cursor[j], n) : 0;
  }
  __syncthreads();
#pragma unroll
  for (int k = 0; k < EPT; ++k) {
    int e = t0 + k * 256 + threadIdx.x;
    if (e < nnz) {
      int r = row[e], c = col[e];
      float v = vals[e];
      int b = r >> BINSHIFT;
      int pos = tb[b] + rank[k];
      pk[pos] = (c << BINSHIFT) | (r & (BINSIZE - 1));
      vv[pos] = v;
    }
  }
}

// ---------- per-bin LDS counting sort -> exact CSR (sc, sv) + base ----------
__global__ __launch_bounds__(256) void csr_sort_kernel(
    const int* __restrict__ bpk, const float* __restrict__ bvv,
    const int* __restrict__ binbase, int* __restrict__ base,
    int* __restrict__ sc, float* __restrict__ sv, int ndst, int nnz) {
  __shared__ int cnt[BINSIZE];
  __shared__ int rk[BINSIZE];
  __shared__ int exc[BINSIZE];
  const int b = blockIdx.x;
  const int t = threadIdx.x;
  const int bb = binbase[b], be = binbase[b + 1];
  if (t < BINSIZE) {
    cnt[t] = 0;
    rk[t] = 0;
  }
  __syncthreads();
  for (int e = bb + t; e < be; e += 256) atomicAdd(&cnt[bpk[e] & (BINSIZE - 1)], 1);
  __syncthreads();
  if (t < BINSIZE) exc[t] = cnt[t];
  __syncthreads();
#pragma unroll
  for (int o = 1; o < BINSIZE; o <<= 1) {
    int v = (t >= o && t < BINSIZE) ? exc[t - o] : 0;
    __syncthreads();
    if (t < BINSIZE) exc[t] += v;
    __syncthreads();
  }
  if (t < BINSIZE) exc[t] -= cnt[t];  // exclusive scan
  __syncthreads();
  const int d0 = b << BINSHIFT;
  if (t < BINSIZE && d0 + t < ndst) base[d0 + t] = bb + exc[t];
  if (b == (int)gridDim.x - 1 && t == 0) base[ndst] = nnz;
  for (int e = bb + t; e < be; e += 256) {
    int p = bpk[e];
    int dl = p & (BINSIZE - 1);
    int pos = bb + exc[dl] + atomicAdd(&rk[dl], 1);
    sc[pos] = p >> BINSHIFT;
    sv[pos] = bvv[e];
  }
}

// ---------- SpMM: one wave per destination row, register accumulate ----------
__global__ __launch_bounds__(512) void spmm_kernel(
    const int* __restrict__ sc, const float* __restrict__ sv,
    const int* __restrict__ base, const float* __restrict__ xT,
    float* __restrict__ accT, int ndst) {
  const int w = __builtin_amdgcn_readfirstlane(threadIdx.x >> 6);  // SGPR
  const int lane = threadIdx.x & 63;
  const int d = blockIdx.x * 8 + w;  // SGPR
  if (d >= ndst) return;
  const int s = base[d], e2 = base[d + 1];  // scalar loads
  float acc = 0.f;
  int j = s;
  for (; j + 8 <= e2; j += 8) {
    int c[8];
    float v[8];
#pragma unroll
    for (int k = 0; k < 8; ++k) {
      c[k] = sc[j + k];  // scalar (SGPR addr) loads
      v[k] = sv[j + k];
    }
    float xv[8];
#pragma unroll
    for (int k = 0; k < 8; ++k) xv[k] = xT[((size_t)c[k] << 6) + lane];
#pragma unroll
    for (int k = 0; k < 8; ++k) acc = fmaf(v[k], xv[k], acc);
  }
  for (; j < e2; ++j) acc = fmaf(sv[j], xT[((size_t)sc[j] << 6) + lane], acc);
  accT[((size_t)d << 6) + lane] = acc;
}

// ---------- accT (ndst, 64) + bias -> out (64, ndst) ----------
__global__ __launch_bounds__(1024) void write_out_kernel(
    const float* __restrict__ accT, const float* __restrict__ bias,
    float* __restrict__ out, int ndst) {
  __shared__ float tile[64][65];
  int d0 = blockIdx.x * 64;
  int tx = threadIdx.x;
  int ty = threadIdx.y;
#pragma unroll
  for (int i = 0; i < 4; ++i) {
    int dl = ty + i * 16;
    int d = d0 + dl;
    tile[tx][dl] = (d < ndst) ? accT[(size_t)d * 64 + tx] : 0.f;  // tx = b
  }
  __syncthreads();
#pragma unroll
  for (int i = 0; i < 4; ++i) {
    int b = ty + i * 16;
    int d = d0 + tx;
    if (d < ndst) out[(size_t)b * ndst + d] = tile[b][tx] + bias[d];
  }
}

extern "C" void kernel_launch(void* const* d_in, const int* in_sizes, int n_in,
                              void* d_out, int out_size, void* d_ws, size_t ws_size,
                              hipStream_t stream) {
  const float* x = (const float*)d_in[0];
  const float* vals = (const float*)d_in[1];
  const float* bias = (const float*)d_in[2];
  const int* row = (const int*)d_in[3];
  const int* col = (const int*)d_in[4];
  float* out = (float*)d_out;

  const int nnz = in_sizes[1];
  const int ndst = in_sizes[2];
  const int B = out_size / ndst;  // == 64 for this problem
  const int nsrc = in_sizes[0] / B;
  const int nbins = (ndst + BINSIZE - 1) >> BINSHIFT;  // 782 <= MAXBINS

  // workspace layout (256B-aligned chunks)
  size_t off = 0;
  auto take = [&](size_t bytes) {
    void* p = (char*)d_ws + off;
    off += (bytes + 255) & ~(size_t)255;
    return p;
  };
  float* xT = (float*)take((size_t)nsrc * 64 * 4);
  int* bpk = (int*)take((size_t)nnz * 4);    // binned packed (c<<7|dloc)
  float* bvv = (float*)take((size_t)nnz * 4);  // binned vals
  int* sc = (int*)take((size_t)nnz * 4);     // CSR cols
  float* sv = (float*)take((size_t)nnz * 4);   // CSR vals
  int* base = (int*)take((size_t)(ndst + 1) * 4);
  int* binbase = (int*)take((size_t)(nbins + 1) * 4);
  int* cursor = (int*)take((size_t)nbins * 4);
  int* binCnt = (int*)take((size_t)nbins * 4);
  // accT aliases [bpk, bvv] (dead after csr_sort): nnz*8 >= ndst*64*4 here
  float* accT = (float*)bpk;
  (void)ws_size;

  hipMemsetAsync(binCnt, 0, (size_t)nbins * 4, stream);

  // 1. transpose x -> xT
  {
    dim3 blk(64, 16);
    int grid = (nsrc + 63) / 64;
    transpose_x_kernel<<<grid, blk, 0, stream>>>(x, xT, nsrc);
  }
  // 2. per-bin histogram
  bin_hist_kernel<<<512, 256, 0, stream>>>(row, binCnt, nnz, nbins);
  // 3. scan -> binbase, cursor
  bin_scan_kernel<<<1, 1024, 0, stream>>>(binCnt, binbase, cursor, nbins, nnz);
  // 4. tile counting-sort scatter into bins (coalesced runs)
  {
    int grid = (nnz + TILE - 1) / TILE;
    bin_scatter_kernel<<<grid, 256, 0, stream>>>(row, col, vals, cursor, bpk,
                                                 bvv, nnz, nbins);
  }
  // 5. per-bin LDS counting sort -> exact CSR + base
  csr_sort_kernel<<<nbins, 256, 0, stream>>>(bpk, bvv, binbase, base, sc, sv,
                                             ndst, nnz);
  // 6. SpMM: one wave per dst row, register accumulate
  {
    int grid = (ndst + 7) / 8;
    spmm_kernel<<<grid, 512, 0, stream>>>(sc, sv, base, xT, accT, ndst);
  }
  // 7. transpose + bias -> out
  {
    dim3 blk(64, 16);
    int grid = (ndst + 63) / 64;
    write_out_kernel<<<grid, blk, 0, stream>>>(accT, bias, out, ndst);
  }
}

// Round 6
// 255.557 us; speedup vs baseline: 5.8526x; 1.1609x over previous
//
#include <hip/hip_runtime.h>

// COO SpMM: out[b,d] = sum_{e: row[e]==d} vals[e] * x[b, col[e]] + bias[d]
// B=64 (one wave), NUM_SRC=NUM_DST=100000, NNZ=3.2M, all fp32.
//
// R6: R5's bin_scatter wrote 178MB (partial-line eviction on 42B runs).
// Fix: scatter to COARSE 256-dst bins with packed int2 (168B runs -> ~40MB),
// then a fused kernel per 128-dst half-bin: LDS counting sort (per-thread
// int atomics) -> register-accumulate spmm reading edges from LDS. Kills
// the sc/sv global round trip and the separate csr_sort kernel.

#define CSHIFT 8
#define CBSIZE 256  // dsts per coarse (stage-A) bin
#define FBSIZE 128  // dsts per stage-B block (half a coarse bin)
#define MAXCB 512
#define TILE 8192
#define EPT 16     // TILE = EPT * 512
#define SCAP 5120  // sedge capacity (mean ~4092 edges, +16 sigma)

// ---------- transpose x (B=64, nsrc) -> xT (nsrc, 64) ----------
__global__ __launch_bounds__(1024) void transpose_x_kernel(
    const float* __restrict__ x, float* __restrict__ xT, int nsrc) {
  __shared__ float tile[64][65];
  int s0 = blockIdx.x * 64;
  int tx = threadIdx.x;  // 0..63
  int ty = threadIdx.y;  // 0..15
#pragma unroll
  for (int i = 0; i < 4; ++i) {
    int b = ty + i * 16;
    int s = s0 + tx;
    tile[tx][b] = (s < nsrc) ? x[(size_t)b * nsrc + s] : 0.f;
  }
  __syncthreads();
#pragma unroll
  for (int i = 0; i < 4; ++i) {
    int sl = ty + i * 16;
    int s = s0 + sl;
    if (s < nsrc) xT[(size_t)s * 64 + tx] = tile[sl][tx];
  }
}

// ---------- coarse-bin histogram (LDS-local, one global merge) ----------
__global__ __launch_bounds__(256) void coarse_hist_kernel(
    const int* __restrict__ row, int* __restrict__ binCnt, int nnz, int ncb) {
  __shared__ int h[MAXCB];
  for (int j = threadIdx.x; j < ncb; j += 256) h[j] = 0;
  __syncthreads();
  int stride = gridDim.x * 256;
  for (int i = blockIdx.x * 256 + threadIdx.x; i < nnz; i += stride)
    atomicAdd(&h[row[i] >> CSHIFT], 1);
  __syncthreads();
  for (int j = threadIdx.x; j < ncb; j += 256) {
    int v = h[j];
    if (v) atomicAdd(&binCnt[j], v);
  }
}

// ---------- exclusive scan of coarse-bin counts -> binbase, cursor ----------
__global__ __launch_bounds__(512) void coarse_scan_kernel(
    const int* __restrict__ binCnt, int* __restrict__ binbase,
    int* __restrict__ cursor, int ncb, int nnz) {
  __shared__ int tmp[512];
  int t = threadIdx.x;
  int v = (t < ncb) ? binCnt[t] : 0;
  tmp[t] = v;
  __syncthreads();
#pragma unroll
  for (int o = 1; o < 512; o <<= 1) {
    int a = (t >= o) ? tmp[t - o] : 0;
    __syncthreads();
    tmp[t] += a;
    __syncthreads();
  }
  if (t < ncb) {
    int ex = tmp[t] - v;
    binbase[t] = ex;
    cursor[t] = ex;
  }
  if (t == 0) binbase[ncb] = nnz;
}

// ---------- tile counting-sort scatter into coarse bins (int2 packed) ----------
// gpk = { (col << 8) | (row & 255), bits(val) }
__global__ __launch_bounds__(512) void coarse_scatter_kernel(
    const int* __restrict__ row, const int* __restrict__ col,
    const float* __restrict__ vals, int* __restrict__ cursor,
    int2* __restrict__ gpk, int nnz, int ncb) {
  __shared__ int cnt[MAXCB];
  __shared__ int tb[MAXCB];
  const int t0 = blockIdx.x * TILE;
  for (int j = threadIdx.x; j < ncb; j += 512) cnt[j] = 0;
  __syncthreads();
  int rank[EPT];
#pragma unroll
  for (int k = 0; k < EPT; ++k) {
    int e = t0 + k * 512 + threadIdx.x;
    if (e < nnz) rank[k] = atomicAdd(&cnt[row[e] >> CSHIFT], 1);
  }
  __syncthreads();
  // one global int cursor atomic per (tile, nonempty bin)
  for (int j = threadIdx.x; j < ncb; j += 512) {
    int n = cnt[j];
    tb[j] = n ? atomicAdd(&cursor[j], n) : 0;
  }
  __syncthreads();
#pragma unroll
  for (int k = 0; k < EPT; ++k) {
    int e = t0 + k * 512 + threadIdx.x;
    if (e < nnz) {
      int r = row[e], c = col[e];
      int b = r >> CSHIFT;
      gpk[tb[b] + rank[k]] =
          make_int2((c << CSHIFT) | (r & (CBSIZE - 1)), __float_as_int(vals[e]));
    }
  }
}

// ---------- fused: LDS counting sort of half-bin + register spmm ----------
__global__ __launch_bounds__(512) void fused_sort_spmm_kernel(
    const int2* __restrict__ gpk, const int* __restrict__ binbase,
    const float* __restrict__ xT, float* __restrict__ accT, int ndst) {
  __shared__ int2 sedge[SCAP];
  __shared__ int cnt[FBSIZE];
  __shared__ int exc[FBSIZE];
  __shared__ int rk[FBSIZE];
  const int cb = blockIdx.x >> 1;
  const int half = blockIdx.x & 1;
  const int t = threadIdx.x;
  const int bb = binbase[cb], be = binbase[cb + 1];
  if (t < FBSIZE) {
    cnt[t] = 0;
    rk[t] = 0;
  }
  __syncthreads();
  // pass 1: histogram this half's dsts
  for (int e = bb + t; e < be; e += 512) {
    int pk = gpk[e].x;
    if (((pk >> 7) & 1) == half) atomicAdd(&cnt[pk & (FBSIZE - 1)], 1);
  }
  __syncthreads();
  if (t < FBSIZE) exc[t] = cnt[t];
  __syncthreads();
#pragma unroll
  for (int o = 1; o < FBSIZE; o <<= 1) {
    int v = (t >= o && t < FBSIZE) ? exc[t - o] : 0;
    __syncthreads();
    if (t < FBSIZE) exc[t] += v;
    __syncthreads();
  }
  if (t < FBSIZE) exc[t] -= cnt[t];  // exclusive
  __syncthreads();
  // pass 2: scatter into LDS in exact per-dst order
  for (int e = bb + t; e < be; e += 512) {
    int2 p = gpk[e];
    if (((p.x >> 7) & 1) == half) {
      int dl = p.x & (FBSIZE - 1);
      int pos = exc[dl] + atomicAdd(&rk[dl], 1);
      sedge[pos] = p;
    }
  }
  __syncthreads();
  // spmm: one wave per dst, register accumulate, edges from LDS
  const int lane = t & 63;
  const int w = t >> 6;  // 0..7
  const int d0 = (cb << CSHIFT) + (half << 7);
  for (int dl = w; dl < FBSIZE; dl += 8) {
    int d = d0 + dl;
    if (d >= ndst) break;  // wave-uniform
    int s = exc[dl];
    int e2 = s + cnt[dl];
    float acc = 0.f;
    int j = s;
    for (; j + 8 <= e2; j += 8) {
      int2 p[8];
#pragma unroll
      for (int k = 0; k < 8; ++k) p[k] = sedge[j + k];  // LDS broadcast
      float xv[8];
#pragma unroll
      for (int k = 0; k < 8; ++k)
        xv[k] = xT[((size_t)(p[k].x >> CSHIFT) << 6) + lane];
#pragma unroll
      for (int k = 0; k < 8; ++k) acc = fmaf(__int_as_float(p[k].y), xv[k], acc);
    }
    for (; j < e2; ++j) {
      int2 p = sedge[j];
      acc = fmaf(__int_as_float(p.y), xT[((size_t)(p.x >> CSHIFT) << 6) + lane],
                 acc);
    }
    accT[((size_t)d << 6) + lane] = acc;
  }
}

// ---------- accT (ndst, 64) + bias -> out (64, ndst) ----------
__global__ __launch_bounds__(1024) void write_out_kernel(
    const float* __restrict__ accT, const float* __restrict__ bias,
    float* __restrict__ out, int ndst) {
  __shared__ float tile[64][65];
  int d0 = blockIdx.x * 64;
  int tx = threadIdx.x;
  int ty = threadIdx.y;
#pragma unroll
  for (int i = 0; i < 4; ++i) {
    int dl = ty + i * 16;
    int d = d0 + dl;
    tile[tx][dl] = (d < ndst) ? accT[(size_t)d * 64 + tx] : 0.f;  // tx = b
  }
  __syncthreads();
#pragma unroll
  for (int i = 0; i < 4; ++i) {
    int b = ty + i * 16;
    int d = d0 + tx;
    if (d < ndst) out[(size_t)b * ndst + d] = tile[b][tx] + bias[d];
  }
}

extern "C" void kernel_launch(void* const* d_in, const int* in_sizes, int n_in,
                              void* d_out, int out_size, void* d_ws, size_t ws_size,
                              hipStream_t stream) {
  const float* x = (const float*)d_in[0];
  const float* vals = (const float*)d_in[1];
  const float* bias = (const float*)d_in[2];
  const int* row = (const int*)d_in[3];
  const int* col = (const int*)d_in[4];
  float* out = (float*)d_out;

  const int nnz = in_sizes[1];
  const int ndst = in_sizes[2];
  const int B = out_size / ndst;  // == 64 for this problem
  const int nsrc = in_sizes[0] / B;
  const int ncb = (ndst + CBSIZE - 1) >> CSHIFT;  // 391 <= MAXCB

  // workspace layout (256B-aligned chunks)
  size_t off = 0;
  auto take = [&](size_t bytes) {
    void* p = (char*)d_ws + off;
    off += (bytes + 255) & ~(size_t)255;
    return p;
  };
  float* xT = (float*)take((size_t)nsrc * 64 * 4);
  int2* gpk = (int2*)take((size_t)nnz * 8);
  float* accT = (float*)take((size_t)ndst * 64 * 4);
  int* binbase = (int*)take((size_t)(ncb + 1) * 4);
  int* cursor = (int*)take((size_t)ncb * 4);
  int* binCnt = (int*)take((size_t)ncb * 4);
  (void)ws_size;

  hipMemsetAsync(binCnt, 0, (size_t)ncb * 4, stream);

  // 1. transpose x -> xT
  {
    dim3 blk(64, 16);
    int grid = (nsrc + 63) / 64;
    transpose_x_kernel<<<grid, blk, 0, stream>>>(x, xT, nsrc);
  }
  // 2. coarse histogram
  coarse_hist_kernel<<<512, 256, 0, stream>>>(row, binCnt, nnz, ncb);
  // 3. scan -> binbase, cursor
  coarse_scan_kernel<<<1, 512, 0, stream>>>(binCnt, binbase, cursor, ncb, nnz);
  // 4. coarse scatter (long runs, packed int2)
  {
    int grid = (nnz + TILE - 1) / TILE;
    coarse_scatter_kernel<<<grid, 512, 0, stream>>>(row, col, vals, cursor, gpk,
                                                    nnz, ncb);
  }
  // 5. fused per-half-bin LDS sort + register spmm
  fused_sort_spmm_kernel<<<2 * ncb, 512, 0, stream>>>(gpk, binbase, xT, accT,
                                                      ndst);
  // 6. transpose + bias -> out
  {
    dim3 blk(64, 16);
    int grid = (ndst + 63) / 64;
    write_out_kernel<<<grid, blk, 0, stream>>>(accT, bias, out, ndst);
  }
}

// Round 7
// 206.974 us; speedup vs baseline: 7.2264x; 1.2347x over previous
//
#include <hip/hip_runtime.h>

// COO SpMM: out[b,d] = sum_{e: row[e]==d} vals[e] * x[b, col[e]] + bias[d]
// B=64 (one wave), NUM_SRC=NUM_DST=100000, NNZ=3.2M, all fp32.
//
// R7: scatter to 128-dst bins (int2, one block reads only its own bin),
// fused bin kernel trimmed to 38.9KB LDS (4 blocks/CU), register
// accumulators + LDS transpose epilogue writing out+bias directly.
// Overflow edges (bin > SCAP, ~never) spill to a global list fixed up
// by a tiny kernel.

#define BSHIFT 7
#define BSIZE 128
#define MAXB 1024
#define TILE 8192
#define EPT 16       // TILE = EPT * 512
#define SCAP 4672    // per-bin LDS edge capacity (mean 4096 + 9 sigma)
#define OVFCAP (1 << 20)

// ---------- transpose x (B=64, nsrc) -> xT (nsrc, 64) ----------
__global__ __launch_bounds__(1024) void transpose_x_kernel(
    const float* __restrict__ x, float* __restrict__ xT, int nsrc) {
  __shared__ float tile[64][65];
  int s0 = blockIdx.x * 64;
  int tx = threadIdx.x;  // 0..63
  int ty = threadIdx.y;  // 0..15
#pragma unroll
  for (int i = 0; i < 4; ++i) {
    int b = ty + i * 16;
    int s = s0 + tx;
    tile[tx][b] = (s < nsrc) ? x[(size_t)b * nsrc + s] : 0.f;
  }
  __syncthreads();
#pragma unroll
  for (int i = 0; i < 4; ++i) {
    int sl = ty + i * 16;
    int s = s0 + sl;
    if (s < nsrc) xT[(size_t)s * 64 + tx] = tile[sl][tx];
  }
}

// ---------- per-bin histogram (LDS-local, one global merge) ----------
__global__ __launch_bounds__(256) void bin_hist_kernel(
    const int* __restrict__ row, int* __restrict__ binCnt, int nnz, int nbins) {
  __shared__ int h[MAXB];
  for (int j = threadIdx.x; j < nbins; j += 256) h[j] = 0;
  __syncthreads();
  int stride = gridDim.x * 256;
  for (int i = blockIdx.x * 256 + threadIdx.x; i < nnz; i += stride)
    atomicAdd(&h[row[i] >> BSHIFT], 1);
  __syncthreads();
  for (int j = threadIdx.x; j < nbins; j += 256) {
    int v = h[j];
    if (v) atomicAdd(&binCnt[j], v);
  }
}

// ---------- exclusive scan of bin counts -> binbase, cursor ----------
__global__ __launch_bounds__(1024) void bin_scan_kernel(
    const int* __restrict__ binCnt, int* __restrict__ binbase,
    int* __restrict__ cursor, int nbins, int nnz) {
  __shared__ int tmp[1024];
  int t = threadIdx.x;
  int v = (t < nbins) ? binCnt[t] : 0;
  tmp[t] = v;
  __syncthreads();
#pragma unroll
  for (int o = 1; o < 1024; o <<= 1) {
    int a = (t >= o) ? tmp[t - o] : 0;
    __syncthreads();
    tmp[t] += a;
    __syncthreads();
  }
  if (t < nbins) {
    int ex = tmp[t] - v;
    binbase[t] = ex;
    cursor[t] = ex;
  }
  if (t == 0) binbase[nbins] = nnz;
}

// ---------- tile counting-sort scatter into 128-dst bins (int2) ----------
// gpk = { (col << 7) | (row & 127), bits(val) }
__global__ __launch_bounds__(512) void bin_scatter_kernel(
    const int* __restrict__ row, const int* __restrict__ col,
    const float* __restrict__ vals, int* __restrict__ cursor,
    int2* __restrict__ gpk, int nnz, int nbins) {
  __shared__ int cnt[MAXB];
  __shared__ int tb[MAXB];
  const int t0 = blockIdx.x * TILE;
  for (int j = threadIdx.x; j < nbins; j += 512) cnt[j] = 0;
  __syncthreads();
  int rank[EPT];
#pragma unroll
  for (int k = 0; k < EPT; ++k) {
    int e = t0 + k * 512 + threadIdx.x;
    if (e < nnz) rank[k] = atomicAdd(&cnt[row[e] >> BSHIFT], 1);
  }
  __syncthreads();
  for (int j = threadIdx.x; j < nbins; j += 512) {
    int n = cnt[j];
    tb[j] = n ? atomicAdd(&cursor[j], n) : 0;
  }
  __syncthreads();
#pragma unroll
  for (int k = 0; k < EPT; ++k) {
    int e = t0 + k * 512 + threadIdx.x;
    if (e < nnz) {
      int r = row[e], c = col[e];
      int b = r >> BSHIFT;
      gpk[tb[b] + rank[k]] =
          make_int2((c << BSHIFT) | (r & (BSIZE - 1)), __float_as_int(vals[e]));
    }
  }
}

// ---------- fused: LDS sort of own bin + register spmm + epilogue ----------
__global__ __launch_bounds__(512) void fused_spmm_kernel(
    const int2* __restrict__ gpk, const int* __restrict__ binbase,
    const float* __restrict__ xT, const float* __restrict__ bias,
    float* __restrict__ out, int2* __restrict__ ovfA, float* __restrict__ ovfB,
    int* __restrict__ ovfCnt, int ndst) {
  __shared__ int2 sedge[SCAP];
  __shared__ int cnt[BSIZE];
  __shared__ int exc[BSIZE];
  __shared__ int rk[BSIZE];
  const int b = blockIdx.x;
  const int t = threadIdx.x;
  const int bb = binbase[b], be = binbase[b + 1];
  const int d0 = b << BSHIFT;
  if (t < BSIZE) {
    cnt[t] = 0;
    rk[t] = 0;
  }
  __syncthreads();
  // pass 1: per-dst histogram
  for (int e = bb + t; e < be; e += 512) atomicAdd(&cnt[gpk[e].x & (BSIZE - 1)], 1);
  __syncthreads();
  if (t < BSIZE) exc[t] = cnt[t];
  __syncthreads();
#pragma unroll
  for (int o = 1; o < BSIZE; o <<= 1) {
    int v = (t >= o && t < BSIZE) ? exc[t - o] : 0;
    __syncthreads();
    if (t < BSIZE) exc[t] += v;
    __syncthreads();
  }
  if (t < BSIZE) exc[t] -= cnt[t];  // exclusive
  __syncthreads();
  // pass 2: scatter into LDS in exact per-dst order
  for (int e = bb + t; e < be; e += 512) {
    int2 p = gpk[e];
    int dl = p.x & (BSIZE - 1);
    int pos = exc[dl] + atomicAdd(&rk[dl], 1);
    if (pos < SCAP) {
      sedge[pos] = p;
    } else {
      int oi = atomicAdd(ovfCnt, 1);
      if (oi < OVFCAP) {
        ovfA[oi] = make_int2(p.x >> BSHIFT, d0 + dl);
        ovfB[oi] = __int_as_float(p.y);
      }
    }
  }
  __syncthreads();
  // spmm: one wave per dst, 16 dsts/wave, register accumulate
  const int lane = t & 63;
  const int w = t >> 6;  // 0..7
  float accq[16];
#pragma unroll
  for (int q = 0; q < 16; ++q) {
    const int dl = w + (q << 3);
    const int s = exc[dl];
    int e2 = s + cnt[dl];
    if (e2 > SCAP) e2 = SCAP;
    float acc = 0.f;
    int j = s;
    for (; j + 8 <= e2; j += 8) {
      int2 p[8];
#pragma unroll
      for (int k = 0; k < 8; ++k) p[k] = sedge[j + k];  // LDS broadcast
      float xv[8];
#pragma unroll
      for (int k = 0; k < 8; ++k)
        xv[k] = xT[((size_t)(p[k].x >> BSHIFT) << 6) + lane];
#pragma unroll
      for (int k = 0; k < 8; ++k) acc = fmaf(__int_as_float(p[k].y), xv[k], acc);
    }
    for (; j < e2; ++j) {
      int2 p = sedge[j];
      acc = fmaf(__int_as_float(p.y), xT[((size_t)(p.x >> BSHIFT) << 6) + lane],
                 acc);
    }
    accq[q] = acc;
  }
  __syncthreads();  // all sedge reads done; reuse as transpose buffer
  float* tr = (float*)sedge;  // 128*65*4 = 33280B <= SCAP*8
#pragma unroll
  for (int q = 0; q < 16; ++q) {
    const int dl = w + (q << 3);
    tr[dl * 65 + lane] = accq[q];
  }
  __syncthreads();
  // epilogue: out[br, d0+dl] = tr[dl][br] + bias[d]
  for (int i = t; i < BSIZE * 64; i += 512) {
    int dl = i & (BSIZE - 1);  // consecutive lanes -> consecutive d
    int br = i >> BSHIFT;
    int d = d0 + dl;
    if (d < ndst) out[(size_t)br * ndst + d] = tr[dl * 65 + br] + bias[d];
  }
}

// ---------- overflow fixup (expected empty) ----------
__global__ __launch_bounds__(256) void ovf_fix_kernel(
    const int2* __restrict__ ovfA, const float* __restrict__ ovfB,
    const int* __restrict__ ovfCnt, const float* __restrict__ xT,
    float* __restrict__ out, int ndst) {
  int n = *ovfCnt;
  if (n > OVFCAP) n = OVFCAP;
  const int lane = threadIdx.x & 63;
  const int w = threadIdx.x >> 6;
  for (int i = w; i < n; i += 4) {
    int2 cd = ovfA[i];
    float v = ovfB[i];
    float xv = xT[((size_t)cd.x << 6) + lane];
    unsafeAtomicAdd(&out[(size_t)lane * ndst + cd.y], v * xv);
  }
}

extern "C" void kernel_launch(void* const* d_in, const int* in_sizes, int n_in,
                              void* d_out, int out_size, void* d_ws, size_t ws_size,
                              hipStream_t stream) {
  const float* x = (const float*)d_in[0];
  const float* vals = (const float*)d_in[1];
  const float* bias = (const float*)d_in[2];
  const int* row = (const int*)d_in[3];
  const int* col = (const int*)d_in[4];
  float* out = (float*)d_out;

  const int nnz = in_sizes[1];
  const int ndst = in_sizes[2];
  const int B = out_size / ndst;  // == 64 for this problem
  const int nsrc = in_sizes[0] / B;
  const int nbins = (ndst + BSIZE - 1) >> BSHIFT;  // 782 <= MAXB

  // workspace layout (256B-aligned chunks)
  size_t off = 0;
  auto take = [&](size_t bytes) {
    void* p = (char*)d_ws + off;
    off += (bytes + 255) & ~(size_t)255;
    return p;
  };
  float* xT = (float*)take((size_t)nsrc * 64 * 4);
  int2* gpk = (int2*)take((size_t)nnz * 8);
  int2* ovfA = (int2*)take((size_t)OVFCAP * 8);
  float* ovfB = (float*)take((size_t)OVFCAP * 4);
  int* binbase = (int*)take((size_t)(nbins + 1) * 4);
  int* cursor = (int*)take((size_t)nbins * 4);
  int* binCnt = (int*)take((size_t)nbins * 4);
  int* ovfCnt = (int*)take(256);
  (void)ws_size;

  hipMemsetAsync(binCnt, 0, (size_t)nbins * 4, stream);
  hipMemsetAsync(ovfCnt, 0, 4, stream);

  // 1. transpose x -> xT
  {
    dim3 blk(64, 16);
    int grid = (nsrc + 63) / 64;
    transpose_x_kernel<<<grid, blk, 0, stream>>>(x, xT, nsrc);
  }
  // 2. per-bin histogram
  bin_hist_kernel<<<512, 256, 0, stream>>>(row, binCnt, nnz, nbins);
  // 3. scan -> binbase, cursor
  bin_scan_kernel<<<1, 1024, 0, stream>>>(binCnt, binbase, cursor, nbins, nnz);
  // 4. scatter into 128-dst bins (int2 packed)
  {
    int grid = (nnz + TILE - 1) / TILE;
    bin_scatter_kernel<<<grid, 512, 0, stream>>>(row, col, vals, cursor, gpk,
                                                 nnz, nbins);
  }
  // 5. fused LDS sort + register spmm + epilogue (writes out + bias)
  fused_spmm_kernel<<<nbins, 512, 0, stream>>>(gpk, binbase, xT, bias, out,
                                               ovfA, ovfB, ovfCnt, ndst);
  // 6. overflow fixup (expected no-op)
  ovf_fix_kernel<<<1, 256, 0, stream>>>(ovfA, ovfB, ovfCnt, xT, out, ndst);
}